// Round 8
// baseline (146.413 us; speedup 1.0000x reference)
//
#include <hip/hip_runtime.h>

#define NSTEP 64
#define HDIM 1024
#define BDIM 2048
#define OHH 511

typedef float v2f __attribute__((ext_vector_type(2)));

__device__ __forceinline__ v2f vsplat(float s) { v2f r; r.x = s; r.y = s; return r; }

// ---------------------------------------------------------------------------
// Kernel 1: precompute transposed coefficient tables.
//   etab[s][k][lane] (float4 c,sn,sp,cp): even pair p = 8*lane+k, cols 2p,2p+1
//   otab same for odd pair j = 8*lane+k (cols 2j+1,2j+2); j==511 -> identity
//   wtab[q][lane] float4 = (cw0,sw0,cw1,sw1) for cols (16*lane+2q, +2q+1)
// __sincosf (native v_sin/v_cos): ~1e-6 per-coeff error, negligible through
// 128 unitary layers; precise sincosf cost ~60 us of the R7 total.
// ---------------------------------------------------------------------------
__global__ void coeff_kernel(const float* __restrict__ omega,
                             const float* __restrict__ ETh,
                             const float* __restrict__ OTh,
                             const float* __restrict__ EPh,
                             const float* __restrict__ OPh,
                             float4* __restrict__ etab,
                             float4* __restrict__ otab,
                             float2* __restrict__ wtab)
{
    int idx = blockIdx.x * 256 + threadIdx.x;
    if (idx < NSTEP * 512) {
        int p = idx & 511;
        float c, s, cp, sp;
        __sincosf(ETh[idx], &s, &c);
        __sincosf(EPh[idx], &sp, &cp);
        etab[(idx & ~511) | ((p & 7) << 6) | (p >> 3)] = make_float4(c, s, sp, cp);
    } else if (idx < 2 * NSTEP * 512) {
        int i2 = idx - NSTEP * 512;
        int l = i2 >> 9;
        int j = i2 & 511;
        float4 v;
        if (j < OHH) {
            float c, s, cp, sp;
            __sincosf(OTh[l * OHH + j], &s, &c);
            __sincosf(OPh[l * OHH + j], &sp, &cp);
            v = make_float4(c, s, sp, cp);
        } else {
            v = make_float4(1.f, 0.f, 1.f, 0.f);  // identity rotation
        }
        otab[(i2 & ~511) | ((j & 7) << 6) | (j >> 3)] = v;
    } else if (idx < 2 * NSTEP * 512 + HDIM) {
        int c = idx - 2 * NSTEP * 512;
        float cw, sw;
        __sincosf(omega[c], &sw, &cw);
        int p = c >> 1;
        wtab[(((p & 7) << 6) | (p >> 3)) * 2 + (c & 1)] = make_float2(cw, sw);
    }
}

// Packed complex pair rotation: state A,B are (re,im) v2f; f = (c,sn,sp,cp).
//   t = c*A - sn*B;  B' = c*B + sn*A;  A' = (sp + i*cp) * t
// A'.re = sp*t.re - cp*t.im ; A'.im = sp*t.im + cp*t.re  -> sp*t + (-cp,cp)*t.yx
__device__ __forceinline__ void pair_rot(const float4 f, v2f& A, v2f& B) {
    v2f C = vsplat(f.x), S = vsplat(f.y);
    v2f t = C * A - S * B;
    B = C * B + S * A;
    v2f cps; cps.x = -f.w; cps.y = f.w;
    A = vsplat(f.z) * t + cps * t.yx;
}
// Right-boundary variant: update A only, Bn is neighbor's value.
__device__ __forceinline__ void pair_rot_a(const float4 f, v2f& A, const v2f Bn) {
    v2f t = vsplat(f.x) * A - vsplat(f.y) * Bn;
    v2f cps; cps.x = -f.w; cps.y = f.w;
    A = vsplat(f.z) * t + cps * t.yx;
}

// ---------------------------------------------------------------------------
// Kernel 2: one wave = ONE row (2048 waves -> 2 waves/SIMD; R7 ran 42% busy
// at 1 wave/SIMD, so a co-resident wave can fill the dep/vmem stalls while
// per-SIMD issue volume stays constant). Lane owns 16 consecutive columns as
// interleaved (re,im) v2f in registers -> packed VOP3P math (R7: 2x win).
// Even pairs lane-internal; odd pairs: 7 internal + 2 boundary via shfl.
// ---------------------------------------------------------------------------
__global__ __launch_bounds__(256) void eunn_kernel(
    const float* __restrict__ x_re,
    const float* __restrict__ x_im,
    const float4* __restrict__ etab,
    const float4* __restrict__ otab,
    const float4* __restrict__ wtab,
    float* __restrict__ out)
{
    const int lane = threadIdx.x & 63;
    const int wave = threadIdx.x >> 6;
    const int row = blockIdx.x * 4 + wave;
    const int colbase = lane << 4;
    const int lanem1 = (lane + 63) & 63;   // oc0 slot: k=7 row of lane-1 (lane0 -> identity)

    v2f x[16];   // interleaved (re, im) state

    // --- load state (f32 planes), interleave into v2f regs ---
    {
        const float4* pr = reinterpret_cast<const float4*>(x_re + row * HDIM + colbase);
        const float4* pi = reinterpret_cast<const float4*>(x_im + row * HDIM + colbase);
        #pragma unroll
        for (int q = 0; q < 4; ++q) {
            float4 vr = pr[q];
            float4 vi = pi[q];
            x[4*q+0].x = vr.x; x[4*q+0].y = vi.x;
            x[4*q+1].x = vr.y; x[4*q+1].y = vi.y;
            x[4*q+2].x = vr.z; x[4*q+2].y = vi.z;
            x[4*q+3].x = vr.w; x[4*q+3].y = vi.w;
        }
    }

    // --- preload even coeffs for step 0 (coalesced: lane-stride 16 B) ---
    float4 ec[8];
    {
        const float4* p = etab + lane;
        #pragma unroll
        for (int k = 0; k < 8; ++k) ec[k] = p[k << 6];
    }

    for (int s = 0; s < NSTEP; ++s) {
        // odd coeffs for this step (consumed after even layer)
        const float4* ob = otab + s * 512;
        float4 oc0 = ob[(7 << 6) + lanem1];
        float4 oc[8];
        #pragma unroll
        for (int k = 0; k < 8; ++k) oc[k] = ob[(k << 6) + lane];

        // ---- even layer, boundary pairs first (k=0,7) so shuffles issue early
        pair_rot(ec[0], x[0],  x[1]);
        pair_rot(ec[7], x[14], x[15]);

        // boundary shuffles on post-even values
        v2f xn, xl;
        xn.x = __shfl_down(x[0].x, 1, 64);   // right neighbor's col0
        xn.y = __shfl_down(x[0].y, 1, 64);
        xl.x = __shfl_up(x[15].x, 1, 64);    // left neighbor's col15
        xl.y = __shfl_up(x[15].y, 1, 64);

        // remaining even pairs k=1..6
        #pragma unroll
        for (int k = 1; k < 7; ++k)
            pair_rot(ec[k], x[2*k], x[2*k+1]);

        // prefetch next step's even coeffs (consumed next iteration)
        if (s + 1 < NSTEP) {
            const float4* p = etab + (s + 1) * 512 + lane;
            #pragma unroll
            for (int k = 0; k < 8; ++k) ec[k] = p[k << 6];
        }

        // ---- odd layer: internal pairs oc[k-1] -> local cols (2k-1, 2k)
        #pragma unroll
        for (int k = 1; k < 8; ++k)
            pair_rot(oc[k-1], x[2*k-1], x[2*k]);
        // right boundary (our col15 = "a", neighbor col0 = "b"): update col15
        pair_rot_a(oc[7], x[15], xn);
        // left boundary (left col15 = "a", our col0 = "b"): update col0
        x[0] = vsplat(oc0.x) * x[0] + vsplat(oc0.y) * xl;
    }

    // --- omega phase + de-interleave + store (coalesced) ---
    float4 wc[8];
    #pragma unroll
    for (int q = 0; q < 8; ++q) wc[q] = wtab[(q << 6) + lane];  // (cw0,sw0,cw1,sw1) cols 2q,2q+1

    float4* pre = reinterpret_cast<float4*>(out + row * HDIM + colbase);
    float4* pim = reinterpret_cast<float4*>(out + BDIM * HDIM + row * HDIM + colbase);
    #pragma unroll
    for (int h = 0; h < 4; ++h) {
        float4 wa = wc[2*h];      // cols 4h, 4h+1
        float4 wb = wc[2*h + 1];  // cols 4h+2, 4h+3
        v2f X0 = x[4*h+0], X1 = x[4*h+1], X2 = x[4*h+2], X3 = x[4*h+3];
        float4 vr, vi;
        vr.x = X0.x * wa.x - X0.y * wa.y;  vi.x = X0.x * wa.y + X0.y * wa.x;
        vr.y = X1.x * wa.z - X1.y * wa.w;  vi.y = X1.x * wa.w + X1.y * wa.z;
        vr.z = X2.x * wb.x - X2.y * wb.y;  vi.z = X2.x * wb.y + X2.y * wb.x;
        vr.w = X3.x * wb.z - X3.y * wb.w;  vi.w = X3.x * wb.w + X3.y * wb.z;
        pre[h] = vr;
        pim[h] = vi;
    }
}

extern "C" void kernel_launch(void* const* d_in, const int* in_sizes, int n_in,
                              void* d_out, int out_size, void* d_ws, size_t ws_size,
                              hipStream_t stream)
{
    const float* x_re  = (const float*)d_in[0];
    const float* x_im  = (const float*)d_in[1];
    const float* omega = (const float*)d_in[2];
    const float* eth   = (const float*)d_in[3];
    const float* oth   = (const float*)d_in[4];
    const float* eph   = (const float*)d_in[5];
    const float* oph   = (const float*)d_in[6];

    char* ws = (char*)d_ws;
    float4* etab = (float4*)ws;                             // 512 KB
    float4* otab = (float4*)(ws + NSTEP * 512 * 16);        // 512 KB
    float2* wtab = (float2*)(ws + 2 * NSTEP * 512 * 16);    // 8 KB

    coeff_kernel<<<260, 256, 0, stream>>>(omega, eth, oth, eph, oph, etab, otab, wtab);
    eunn_kernel<<<BDIM / 4, 256, 0, stream>>>(x_re, x_im, etab, otab,
                                              (const float4*)wtab, (float*)d_out);
}

// Round 9
// 133.687 us; speedup vs baseline: 1.0952x; 1.0952x over previous
//
#include <hip/hip_runtime.h>

#define NSTEP 64
#define HDIM 1024
#define BDIM 2048
#define OHH 511

typedef float v2f __attribute__((ext_vector_type(2)));

__device__ __forceinline__ v2f vsplat(float s) { v2f r; r.x = s; r.y = s; return r; }

// ---------------------------------------------------------------------------
// Kernel 1: precompute transposed coefficient tables.
//   etab[s][k][lane] (float4 c,sn,sp,cp): even pair p = 8*lane+k, cols 2p,2p+1
//   otab same for odd pair j = 8*lane+k (cols 2j+1,2j+2); j==511 -> identity
//   wtab[q][lane] float4 = (cw0,sw0,cw1,sw1) for cols (16*lane+2q, +2q+1)
// ---------------------------------------------------------------------------
__global__ void coeff_kernel(const float* __restrict__ omega,
                             const float* __restrict__ ETh,
                             const float* __restrict__ OTh,
                             const float* __restrict__ EPh,
                             const float* __restrict__ OPh,
                             float4* __restrict__ etab,
                             float4* __restrict__ otab,
                             float2* __restrict__ wtab)
{
    int idx = blockIdx.x * 256 + threadIdx.x;
    if (idx < NSTEP * 512) {
        int p = idx & 511;
        float c, s, cp, sp;
        __sincosf(ETh[idx], &s, &c);
        __sincosf(EPh[idx], &sp, &cp);
        etab[(idx & ~511) | ((p & 7) << 6) | (p >> 3)] = make_float4(c, s, sp, cp);
    } else if (idx < 2 * NSTEP * 512) {
        int i2 = idx - NSTEP * 512;
        int l = i2 >> 9;
        int j = i2 & 511;
        float4 v;
        if (j < OHH) {
            float c, s, cp, sp;
            __sincosf(OTh[l * OHH + j], &s, &c);
            __sincosf(OPh[l * OHH + j], &sp, &cp);
            v = make_float4(c, s, sp, cp);
        } else {
            v = make_float4(1.f, 0.f, 1.f, 0.f);  // identity rotation
        }
        otab[(i2 & ~511) | ((j & 7) << 6) | (j >> 3)] = v;
    } else if (idx < 2 * NSTEP * 512 + HDIM) {
        int c = idx - 2 * NSTEP * 512;
        float cw, sw;
        __sincosf(omega[c], &sw, &cw);
        int p = c >> 1;
        wtab[(((p & 7) << 6) | (p >> 3)) * 2 + (c & 1)] = make_float2(cw, sw);
    }
}

// Packed complex pair rotation: state A,B are (re,im) v2f; f = (c,sn,sp,cp).
//   t = c*A - sn*B;  B' = c*B + sn*A;  A' = (sp + i*cp) * t
__device__ __forceinline__ void pair_rot(const float4 f, v2f& A, v2f& B) {
    v2f C = vsplat(f.x), S = vsplat(f.y);
    v2f t = C * A - S * B;
    B = C * B + S * A;
    v2f cps; cps.x = -f.w; cps.y = f.w;
    A = vsplat(f.z) * t + cps * t.yx;
}
// Right-boundary variant: update A only, Bn is neighbor's value.
__device__ __forceinline__ void pair_rot_a(const float4 f, v2f& A, const v2f Bn) {
    v2f t = vsplat(f.x) * A - vsplat(f.y) * Bn;
    v2f cps; cps.x = -f.w; cps.y = f.w;
    A = vsplat(f.z) * t + cps * t.yx;
}

// ---------------------------------------------------------------------------
// Kernel 2: R7 champion structure (one wave = 2 rows, 1024 waves = 1 block/CU,
// all 4 waves step-synchronized so the 17KB/step table slice stays L1-hot;
// packed v2f math). NEW in R9: the odd-layer coefficients (oc, oc0) are
// prefetched at the BOTTOM of the previous step (prologue loads step 0), so
// every vmem result has >=600 cycles between issue and first use — even a
// conservative compiler vmcnt(0) costs nothing. Zero extra registers
// (single coeff set each, overwritten after last consume; VMEM WAR is free).
// ---------------------------------------------------------------------------
__global__ __launch_bounds__(256) void eunn_kernel(
    const float* __restrict__ x_re,
    const float* __restrict__ x_im,
    const float4* __restrict__ etab,
    const float4* __restrict__ otab,
    const float4* __restrict__ wtab,
    float* __restrict__ out)
{
    const int lane = threadIdx.x & 63;
    const int wave = threadIdx.x >> 6;
    const int row0 = blockIdx.x * 8 + wave * 2;
    const int colbase = lane << 4;
    const int lanem1 = (lane + 63) & 63;   // oc0 slot: k=7 row of lane-1 (lane0 -> identity)

    v2f x[2][16];   // interleaved (re, im) state

    // --- load state (f32 planes), interleave into v2f regs ---
    #pragma unroll
    for (int r = 0; r < 2; ++r) {
        const float4* pr = reinterpret_cast<const float4*>(x_re + (row0 + r) * HDIM + colbase);
        const float4* pi = reinterpret_cast<const float4*>(x_im + (row0 + r) * HDIM + colbase);
        #pragma unroll
        for (int q = 0; q < 4; ++q) {
            float4 vr = pr[q];
            float4 vi = pi[q];
            x[r][4*q+0].x = vr.x; x[r][4*q+0].y = vi.x;
            x[r][4*q+1].x = vr.y; x[r][4*q+1].y = vi.y;
            x[r][4*q+2].x = vr.z; x[r][4*q+2].y = vi.z;
            x[r][4*q+3].x = vr.w; x[r][4*q+3].y = vi.w;
        }
    }

    // --- prologue: load step-0 even AND odd coeffs (coalesced, lane-stride 16B)
    float4 ec[8], oc[8], oc0;
    {
        const float4* pe = etab + lane;
        const float4* po = otab + lane;
        #pragma unroll
        for (int k = 0; k < 8; ++k) { ec[k] = pe[k << 6]; oc[k] = po[k << 6]; }
        oc0 = otab[(7 << 6) + lanem1];
    }

    for (int s = 0; s < NSTEP; ++s) {
        // ---- even layer, boundary pairs first (k=0,7) so shuffles issue early
        pair_rot(ec[0], x[0][0],  x[0][1]);
        pair_rot(ec[0], x[1][0],  x[1][1]);
        pair_rot(ec[7], x[0][14], x[0][15]);
        pair_rot(ec[7], x[1][14], x[1][15]);

        // boundary shuffles on post-even values
        v2f xn[2], xl[2];
        #pragma unroll
        for (int r = 0; r < 2; ++r) {
            xn[r].x = __shfl_down(x[r][0].x, 1, 64);   // right neighbor's col0
            xn[r].y = __shfl_down(x[r][0].y, 1, 64);
            xl[r].x = __shfl_up(x[r][15].x, 1, 64);    // left neighbor's col15
            xl[r].y = __shfl_up(x[r][15].y, 1, 64);
        }

        // remaining even pairs k=1..6
        #pragma unroll
        for (int k = 1; k < 7; ++k) {
            pair_rot(ec[k], x[0][2*k], x[0][2*k+1]);
            pair_rot(ec[k], x[1][2*k], x[1][2*k+1]);
        }

        const int sn = (s + 1 < NSTEP) ? (s + 1) : (NSTEP - 1);

        // prefetch next step's even coeffs (ec fully consumed above)
        {
            const float4* p = etab + sn * 512 + lane;
            #pragma unroll
            for (int k = 0; k < 8; ++k) ec[k] = p[k << 6];
        }

        // ---- odd layer: internal pairs oc[k-1] -> local cols (2k-1, 2k)
        #pragma unroll
        for (int k = 1; k < 8; ++k) {
            pair_rot(oc[k-1], x[0][2*k-1], x[0][2*k]);
            pair_rot(oc[k-1], x[1][2*k-1], x[1][2*k]);
        }
        // right boundary (our col15 = "a", neighbor col0 = "b"): update col15
        pair_rot_a(oc[7], x[0][15], xn[0]);
        pair_rot_a(oc[7], x[1][15], xn[1]);
        // left boundary (left col15 = "a", our col0 = "b"): update col0
        {
            v2f C = vsplat(oc0.x), S = vsplat(oc0.y);
            x[0][0] = C * x[0][0] + S * xl[0];
            x[1][0] = C * x[1][0] + S * xl[1];
        }

        // prefetch next step's odd coeffs at step BOTTOM (oc fully consumed;
        // first use is after next step's even layer -> ~600+ cyc of cover)
        {
            const float4* p = otab + sn * 512 + lane;
            #pragma unroll
            for (int k = 0; k < 8; ++k) oc[k] = p[k << 6];
            oc0 = p[(7 << 6) + lanem1 - lane];
        }
    }

    // --- omega phase + de-interleave + store (coalesced) ---
    float4 wc[8];
    #pragma unroll
    for (int q = 0; q < 8; ++q) wc[q] = wtab[(q << 6) + lane];  // (cw0,sw0,cw1,sw1) cols 2q,2q+1

    #pragma unroll
    for (int r = 0; r < 2; ++r) {
        float4* pre = reinterpret_cast<float4*>(out + (row0 + r) * HDIM + colbase);
        float4* pim = reinterpret_cast<float4*>(out + BDIM * HDIM + (row0 + r) * HDIM + colbase);
        #pragma unroll
        for (int h = 0; h < 4; ++h) {
            float4 wa = wc[2*h];      // cols 4h, 4h+1
            float4 wb = wc[2*h + 1];  // cols 4h+2, 4h+3
            v2f X0 = x[r][4*h+0], X1 = x[r][4*h+1], X2 = x[r][4*h+2], X3 = x[r][4*h+3];
            float4 vr, vi;
            vr.x = X0.x * wa.x - X0.y * wa.y;  vi.x = X0.x * wa.y + X0.y * wa.x;
            vr.y = X1.x * wa.z - X1.y * wa.w;  vi.y = X1.x * wa.w + X1.y * wa.z;
            vr.z = X2.x * wb.x - X2.y * wb.y;  vi.z = X2.x * wb.y + X2.y * wb.x;
            vr.w = X3.x * wb.z - X3.y * wb.w;  vi.w = X3.x * wb.w + X3.y * wb.z;
            pre[h] = vr;
            pim[h] = vi;
        }
    }
}

extern "C" void kernel_launch(void* const* d_in, const int* in_sizes, int n_in,
                              void* d_out, int out_size, void* d_ws, size_t ws_size,
                              hipStream_t stream)
{
    const float* x_re  = (const float*)d_in[0];
    const float* x_im  = (const float*)d_in[1];
    const float* omega = (const float*)d_in[2];
    const float* eth   = (const float*)d_in[3];
    const float* oth   = (const float*)d_in[4];
    const float* eph   = (const float*)d_in[5];
    const float* oph   = (const float*)d_in[6];

    char* ws = (char*)d_ws;
    float4* etab = (float4*)ws;                             // 512 KB
    float4* otab = (float4*)(ws + NSTEP * 512 * 16);        // 512 KB
    float2* wtab = (float2*)(ws + 2 * NSTEP * 512 * 16);    // 8 KB

    coeff_kernel<<<260, 256, 0, stream>>>(omega, eth, oth, eph, oph, etab, otab, wtab);
    eunn_kernel<<<BDIM / 8, 256, 0, stream>>>(x_re, x_im, etab, otab,
                                              (const float4*)wtab, (float*)d_out);
}